// Round 4
// baseline (1370.998 us; speedup 1.0000x reference)
//
#include <hip/hip_runtime.h>
#include <hip/hip_fp16.h>
#include <math.h>

#define NK 27
#define C1 128
#define C2 14
#define X1S 16        // x1 row stride (floats)
#define WIN 1024      // dst-window for conv1A
#define TS 28         // table stride in int2 entries (27 used + 1 pad)

union H8 { uint4 u; __half h[8]; };

// ---------- per-map valid counts (out_idx[m] sorted, pads==N at end) + offsets ----------
__global__ __launch_bounds__(64) void cnt_off_kernel(
    const int* __restrict__ out_idx, int* __restrict__ off, int N)
{
    __shared__ int cnt_s[NK];
    int t = threadIdx.x;
    if (t < NK) {
        const int* a = out_idx + (size_t)t * N;
        int lo = 0, hi = N;
        while (lo < hi) { int mid = (lo + hi) >> 1; if (a[mid] < N) lo = mid + 1; else hi = mid; }
        cnt_s[t] = lo;
    }
    __syncthreads();
    if (t == 0) {
        int run = 0;
        for (int m = 0; m < NK; ++m) { off[m] = run; run += cnt_s[m]; }
        off[NK] = run;
    }
}

// ---------- per-(map,window) j-ranges via binary search on out_idx values ----------
__global__ __launch_bounds__(256) void ranges_kernel(
    const int* __restrict__ out_idx, int* __restrict__ r, int N, int nwin)
{
    int t = blockIdx.x * 256 + threadIdx.x;
    int total = NK * (nwin + 1);
    if (t >= total) return;
    int mm = t / (nwin + 1);
    int b  = t % (nwin + 1);
    long tgt_l = (long)b * WIN; if (tgt_l > N) tgt_l = N;
    int target = (int)tgt_l;
    const int* a = out_idx + (size_t)mm * N;
    int lo = 0, hi = N;
    while (lo < hi) { int mid = (lo + hi) >> 1; if (a[mid] < target) lo = mid + 1; else hi = mid; }
    r[t] = lo;
}

// ---------- combined inverse table: T[v*TS+mm] = (P slot, gather src) ----------
__global__ __launch_bounds__(256) void table_kernel(
    const int* __restrict__ in_idx, const int* __restrict__ out_idx,
    const int* __restrict__ off, int2* __restrict__ T,
    long capRows, int N)
{
    const int mm = blockIdx.x;
    const int j0 = blockIdx.y * 256;
    const int* src = in_idx + (size_t)mm * N;
    if (src[j0] >= N) return;              // padded suffix (prefix property)
    int j = j0 + threadIdx.x;
    if (j >= N) return;
    int v = src[j];
    if (v >= N) return;
    long slot = (long)off[mm] + j;
    int s32 = (slot < capRows) ? (int)slot : -1;
    T[(size_t)v * TS + mm] = make_int2(s32, out_idx[(size_t)mm * N + j]);
}

// ---------- conv1 phase A: windowed sequential gather + GEMM -> fp16 pair buffer ----------
// 4 CONSECUTIVE pairs per thread: 448 ds_read_b128 amortize over 4x1792 FMAs.
__global__ __launch_bounds__(256) void conv1A_kernel(
    const float* __restrict__ feat, const float* __restrict__ W1,
    const int* __restrict__ out_idx, const int* __restrict__ r,
    const int* __restrict__ off, __half* __restrict__ P,
    long capRows, int N, int nwin)
{
    const int mm = blockIdx.x;
    const int b  = blockIdx.y;
    const int jlo = r[mm * (nwin + 1) + b];
    const int jhi = r[mm * (nwin + 1) + b + 1];
    if (jlo >= jhi) return;                // block-uniform

    __shared__ float Wl[C2 * C1];          // Wl[c*128+i] = W1[26-mm][i][c]
    const int k = 26 - mm;
    const int tid = threadIdx.x;
    for (int t = tid; t < C2 * C1; t += 256) {
        int c = t >> 7, i = t & 127;
        Wl[t] = W1[k * (C1 * C2) + i * C2 + c];
    }
    __syncthreads();

    const int base = off[mm];
    const int* gidx = out_idx + (size_t)mm * N;

    for (int j0 = jlo + tid * 4; j0 < jhi; j0 += 1024) {
        bool val[4];
        int v[4];
        #pragma unroll
        for (int p = 0; p < 4; ++p) {
            val[p] = (j0 + p < jhi);
            v[p]   = gidx[val[p] ? (j0 + p) : j0];
        }

        const float4* fa = (const float4*)(feat + (size_t)v[0] * C1);
        const float4* fb = (const float4*)(feat + (size_t)v[1] * C1);
        const float4* fc = (const float4*)(feat + (size_t)v[2] * C1);
        const float4* fd = (const float4*)(feat + (size_t)v[3] * C1);

        float acc[4][C2];
        #pragma unroll
        for (int p = 0; p < 4; ++p)
            #pragma unroll
            for (int c = 0; c < C2; ++c) acc[p][c] = 0.f;

        for (int i4 = 0; i4 < C1 / 4; ++i4) {
            float4 a  = fa[i4];
            float4 bb = fb[i4];
            float4 cc = fc[i4];
            float4 d  = fd[i4];
            #pragma unroll
            for (int c = 0; c < C2; ++c) {
                float4 w = *(const float4*)&Wl[c * C1 + i4 * 4];
                acc[0][c] = fmaf(a.x,  w.x, fmaf(a.y,  w.y, fmaf(a.z,  w.z, fmaf(a.w,  w.w, acc[0][c]))));
                acc[1][c] = fmaf(bb.x, w.x, fmaf(bb.y, w.y, fmaf(bb.z, w.z, fmaf(bb.w, w.w, acc[1][c]))));
                acc[2][c] = fmaf(cc.x, w.x, fmaf(cc.y, w.y, fmaf(cc.z, w.z, fmaf(cc.w, w.w, acc[2][c]))));
                acc[3][c] = fmaf(d.x,  w.x, fmaf(d.y,  w.y, fmaf(d.z,  w.z, fmaf(d.w,  w.w, acc[3][c]))));
            }
        }

        #pragma unroll
        for (int p = 0; p < 4; ++p) {
            if (!val[p]) continue;
            long slot = (long)base + (j0 + p);
            if (slot >= capRows) continue;
            H8 ha, hb;
            #pragma unroll
            for (int c = 0; c < 8; ++c) ha.h[c] = __float2half(acc[p][c]);
            #pragma unroll
            for (int c = 0; c < 6; ++c) hb.h[c] = __float2half(acc[p][8 + c]);
            hb.h[6] = __half(0.f); hb.h[7] = __half(0.f);
            uint4* dst = (uint4*)(P + (size_t)slot * 16);
            dst[0] = ha.u;
            dst[1] = hb.u;
        }
    }
}

// ---------- conv1 phase B: per-voxel sum of P rows (L3 gathers) + GELU -> x1 ----------
__global__ __launch_bounds__(256) void conv1B_kernel(
    const __half* __restrict__ P, const int2* __restrict__ T,
    float* __restrict__ x1, int N)
{
    int v = blockIdx.x * 256 + threadIdx.x;
    if (v >= N) return;

    int s[NK];
    const int4* t4 = (const int4*)(T + (size_t)v * TS);
    #pragma unroll
    for (int q = 0; q < 13; ++q) {
        int4 t = t4[q];
        s[2 * q] = t.x; s[2 * q + 1] = t.z;
    }
    { int4 t = t4[13]; s[26] = t.x; }

    float acc[C2];
    #pragma unroll
    for (int c = 0; c < C2; ++c) acc[c] = 0.f;

    for (int c0 = 0; c0 < NK; c0 += 9) {
        int nq = (c0 + 9 <= NK) ? 9 : (NK - c0);
        uint4 ua[9], ub[9];
        #pragma unroll
        for (int q = 0; q < 9; ++q) {
            int sl = (q < nq) ? s[c0 + q] : -1;
            if (sl >= 0) {
                const uint4* pr = (const uint4*)(P + (size_t)sl * 16);
                ua[q] = pr[0];
                ub[q] = pr[1];
            } else {
                ua[q] = make_uint4(0, 0, 0, 0);
                ub[q] = make_uint4(0, 0, 0, 0);
            }
        }
        #pragma unroll
        for (int q = 0; q < 9; ++q) {
            H8 a, b2;
            a.u = ua[q]; b2.u = ub[q];
            #pragma unroll
            for (int c = 0; c < 8; ++c) acc[c] += __half2float(a.h[c]);
            #pragma unroll
            for (int c = 0; c < 6; ++c) acc[8 + c] += __half2float(b2.h[c]);
        }
    }

    #pragma unroll
    for (int c = 0; c < C2; ++c) {
        float x = acc[c];
        acc[c] = 0.5f * x * (1.0f + erff(x * 0.70710678118654752f));
    }
    float* o = x1 + (size_t)v * X1S;
    *(float4*)(o + 0)  = make_float4(acc[0], acc[1], acc[2], acc[3]);
    *(float4*)(o + 4)  = make_float4(acc[4], acc[5], acc[6], acc[7]);
    *(float4*)(o + 8)  = make_float4(acc[8], acc[9], acc[10], acc[11]);
    *(float4*)(o + 12) = make_float4(acc[12], acc[13], 0.f, 0.f);
}

// ---------- conv2 direct: per output voxel, gather x1 neighbors (L3) + 14x14x27 ----------
__global__ __launch_bounds__(256) void conv2_kernel(
    const float* __restrict__ x1, const float* __restrict__ W2,
    const int2* __restrict__ T, float* __restrict__ out, int N)
{
    __shared__ float Wl[NK * C2 * 16];    // Wl[(mm*14+i)*16 + c] = W2[26-mm][i][c]
    const int tid = threadIdx.x;
    for (int t = tid; t < NK * C2 * C2; t += 256) {
        int mm = t / (C2 * C2);
        int rr = t % (C2 * C2);
        int i = rr / C2, c = rr % C2;
        Wl[(mm * C2 + i) * 16 + c] = W2[(26 - mm) * (C2 * C2) + rr];
    }
    __syncthreads();

    const int v0 = blockIdx.x * 1024 + tid * 4;
    if (v0 >= N) return;
    bool vv[4];
    #pragma unroll
    for (int p = 0; p < 4; ++p) vv[p] = (v0 + p < N);

    float acc[4][C2];
    #pragma unroll
    for (int p = 0; p < 4; ++p)
        #pragma unroll
        for (int c = 0; c < C2; ++c) acc[p][c] = 0.f;

    for (int c0 = 0; c0 < NK; c0 += 9) {
        int nq = (c0 + 9 <= NK) ? 9 : (NK - c0);
        int s[4][9];
        #pragma unroll
        for (int p = 0; p < 4; ++p) {
            const int2* tr = T + (size_t)(v0 + p) * TS + c0;
            #pragma unroll
            for (int q = 0; q < 9; ++q)
                s[p][q] = (vv[p] && q < nq) ? tr[q].y : -1;
        }
        for (int q = 0; q < nq; ++q) {
            int m = c0 + q;
            float xr[4][C2];
            #pragma unroll
            for (int p = 0; p < 4; ++p) {
                int sl = s[p][q];
                if (sl >= 0 && sl < N) {
                    const float* rrow = x1 + (size_t)sl * X1S;
                    float4 q0 = *(const float4*)(rrow + 0);
                    float4 q1 = *(const float4*)(rrow + 4);
                    float4 q2 = *(const float4*)(rrow + 8);
                    float2 q3 = *(const float2*)(rrow + 12);
                    xr[p][0]=q0.x; xr[p][1]=q0.y; xr[p][2]=q0.z; xr[p][3]=q0.w;
                    xr[p][4]=q1.x; xr[p][5]=q1.y; xr[p][6]=q1.z; xr[p][7]=q1.w;
                    xr[p][8]=q2.x; xr[p][9]=q2.y; xr[p][10]=q2.z; xr[p][11]=q2.w;
                    xr[p][12]=q3.x; xr[p][13]=q3.y;
                } else {
                    #pragma unroll
                    for (int i = 0; i < C2; ++i) xr[p][i] = 0.f;
                }
            }
            #pragma unroll
            for (int i = 0; i < C2; ++i) {
                const float* wr = &Wl[(m * C2 + i) * 16];
                float4 w0 = *(const float4*)(wr + 0);
                float4 w1 = *(const float4*)(wr + 4);
                float4 w2 = *(const float4*)(wr + 8);
                float2 w3 = *(const float2*)(wr + 12);
                #pragma unroll
                for (int p = 0; p < 4; ++p) {
                    float xv = xr[p][i];
                    acc[p][0]  = fmaf(xv, w0.x, acc[p][0]);
                    acc[p][1]  = fmaf(xv, w0.y, acc[p][1]);
                    acc[p][2]  = fmaf(xv, w0.z, acc[p][2]);
                    acc[p][3]  = fmaf(xv, w0.w, acc[p][3]);
                    acc[p][4]  = fmaf(xv, w1.x, acc[p][4]);
                    acc[p][5]  = fmaf(xv, w1.y, acc[p][5]);
                    acc[p][6]  = fmaf(xv, w1.z, acc[p][6]);
                    acc[p][7]  = fmaf(xv, w1.w, acc[p][7]);
                    acc[p][8]  = fmaf(xv, w2.x, acc[p][8]);
                    acc[p][9]  = fmaf(xv, w2.y, acc[p][9]);
                    acc[p][10] = fmaf(xv, w2.z, acc[p][10]);
                    acc[p][11] = fmaf(xv, w2.w, acc[p][11]);
                    acc[p][12] = fmaf(xv, w3.x, acc[p][12]);
                    acc[p][13] = fmaf(xv, w3.y, acc[p][13]);
                }
            }
        }
    }

    #pragma unroll
    for (int p = 0; p < 4; ++p) {
        if (!vv[p]) continue;
        float* o = out + (size_t)(v0 + p) * C2;
        *(float2*)(o + 0)  = make_float2(acc[p][0], acc[p][1]);
        *(float2*)(o + 2)  = make_float2(acc[p][2], acc[p][3]);
        *(float2*)(o + 4)  = make_float2(acc[p][4], acc[p][5]);
        *(float2*)(o + 6)  = make_float2(acc[p][6], acc[p][7]);
        *(float2*)(o + 8)  = make_float2(acc[p][8], acc[p][9]);
        *(float2*)(o + 10) = make_float2(acc[p][10], acc[p][11]);
        *(float2*)(o + 12) = make_float2(acc[p][12], acc[p][13]);
    }
}

// ================= fallback (round-1 path, needs only 25.6MB ws) =================
__global__ __launch_bounds__(256) void fb_conv1_kernel(
    const float* __restrict__ feat, const float* __restrict__ W1,
    const int* __restrict__ in_idx, const int* __restrict__ out_idx,
    float* __restrict__ x1, int N)
{
    __shared__ float Wl[C2 * C1];
    const int k = blockIdx.y;
    const int tid = threadIdx.x;
    for (int t = tid; t < C2 * C1; t += 256) {
        int c = t >> 7, i = t & 127;
        Wl[t] = W1[k * (C1 * C2) + i * C2 + c];
    }
    __syncthreads();
    const int j = blockIdx.x * 256 + tid;
    if (j >= N) return;
    int src = in_idx[(size_t)k * N + j];
    int dst = out_idx[(size_t)k * N + j];
    if (dst >= N) return;
    const float4* f = (const float4*)(feat + (size_t)src * C1);
    float acc[C2];
    for (int c = 0; c < C2; ++c) acc[c] = 0.f;
    for (int i4 = 0; i4 < C1 / 4; ++i4) {
        float4 a = f[i4];
        for (int c = 0; c < C2; ++c) {
            float4 w = *(const float4*)&Wl[c * C1 + i4 * 4];
            acc[c] = fmaf(a.x, w.x, fmaf(a.y, w.y, fmaf(a.z, w.z, fmaf(a.w, w.w, acc[c]))));
        }
    }
    float* o = x1 + (size_t)dst * X1S;
    for (int c = 0; c < C2; ++c) atomicAdd(o + c, acc[c]);
}

__global__ __launch_bounds__(256) void fb_gelu_kernel(float* __restrict__ x, int total4)
{
    int i = blockIdx.x * 256 + threadIdx.x;
    if (i >= total4) return;
    float4 v = ((float4*)x)[i];
    v.x = 0.5f * v.x * (1.0f + erff(v.x * 0.70710678118654752f));
    v.y = 0.5f * v.y * (1.0f + erff(v.y * 0.70710678118654752f));
    v.z = 0.5f * v.z * (1.0f + erff(v.z * 0.70710678118654752f));
    v.w = 0.5f * v.w * (1.0f + erff(v.w * 0.70710678118654752f));
    ((float4*)x)[i] = v;
}

__global__ __launch_bounds__(256) void fb_conv2_kernel(
    const float* __restrict__ x1, const float* __restrict__ W2,
    const int* __restrict__ in_idx, const int* __restrict__ out_idx,
    float* __restrict__ out, int N)
{
    __shared__ float Wl[C2 * 16];
    const int k = blockIdx.y;
    const int tid = threadIdx.x;
    if (tid < C2 * C2) {
        int c = tid / C2, i = tid % C2;
        Wl[c * 16 + i] = W2[k * (C2 * C2) + i * C2 + c];
    }
    __syncthreads();
    const int j = blockIdx.x * 256 + tid;
    if (j >= N) return;
    int src = in_idx[(size_t)k * N + j];
    int dst = out_idx[(size_t)k * N + j];
    if (dst >= N) return;
    const float* rrow = x1 + (size_t)src * X1S;
    float f[C2];
    for (int i = 0; i < C2; ++i) f[i] = rrow[i];
    float* o = out + (size_t)dst * C2;
    for (int c = 0; c < C2; ++c) {
        float sum = 0.f;
        for (int i = 0; i < C2; ++i) sum = fmaf(f[i], Wl[c * 16 + i], sum);
        atomicAdd(o + c, sum);
    }
}

// ================================ launcher ================================
extern "C" void kernel_launch(void* const* d_in, const int* in_sizes, int n_in,
                              void* d_out, int out_size, void* d_ws, size_t ws_size,
                              hipStream_t stream)
{
    const float* feat    = (const float*)d_in[0];
    const float* W1      = (const float*)d_in[1];
    const float* W2      = (const float*)d_in[2];
    const int*   in_idx  = (const int*)d_in[3];
    const int*   out_idx = (const int*)d_in[4];
    float*       out     = (float*)d_out;

    const int N    = in_sizes[0] / C1;               // 400000
    const int nwin = (N + WIN - 1) / WIN;

    const size_t t_bytes   = (size_t)N * TS * sizeof(int2);    // 89.6 MB
    const size_t x1_bytes  = (size_t)N * X1S * sizeof(float);  // 25.6 MB
    const size_t r_bytes   = ((size_t)NK * (nwin + 1) * sizeof(int) + 255) & ~255ull;
    const size_t off_bytes = 256;
    const size_t fixed     = t_bytes + x1_bytes + r_bytes + off_bytes;

    long capRows = 0;
    if (ws_size > fixed) capRows = (long)((ws_size - fixed) / 32);  // fp16 rows of 32B
    long maxRows = (long)NK * N;
    if (capRows > maxRows) capRows = maxRows;

    if (capRows >= 3000000L) {
        char* w = (char*)d_ws;
        int2*  T   = (int2*)w;              w += t_bytes;
        float* x1  = (float*)w;             w += x1_bytes;
        int*   r   = (int*)w;               w += r_bytes;
        int*   off = (int*)w;               w += off_bytes;
        __half* P  = (__half*)w;

        hipMemsetAsync(T, 0xFF, t_bytes, stream);

        cnt_off_kernel<<<1, 64, 0, stream>>>(out_idx, off, N);

        int rtot = NK * (nwin + 1);
        ranges_kernel<<<(rtot + 255) / 256, 256, 0, stream>>>(out_idx, r, N, nwin);

        {
            dim3 grid(NK, (N + 255) / 256);
            table_kernel<<<grid, 256, 0, stream>>>(in_idx, out_idx, off, T, capRows, N);
        }
        {
            dim3 grid(NK, nwin);
            conv1A_kernel<<<grid, 256, 0, stream>>>(feat, W1, out_idx, r, off, P, capRows, N, nwin);
        }
        conv1B_kernel<<<(N + 255) / 256, 256, 0, stream>>>(P, T, x1, N);
        conv2_kernel<<<(N + 1023) / 1024, 256, 0, stream>>>(x1, W2, T, out, N);
    } else {
        float* x1 = (float*)d_ws;
        hipMemsetAsync(x1, 0, x1_bytes, stream);
        hipMemsetAsync(out, 0, (size_t)out_size * sizeof(float), stream);
        {
            dim3 grid((N + 255) / 256, NK);
            fb_conv1_kernel<<<grid, 256, 0, stream>>>(feat, W1, in_idx, out_idx, x1, N);
        }
        {
            int total4 = N * X1S / 4;
            fb_gelu_kernel<<<(total4 + 255) / 256, 256, 0, stream>>>(x1, total4);
        }
        {
            dim3 grid((N + 255) / 256, NK);
            fb_conv2_kernel<<<grid, 256, 0, stream>>>(x1, W2, in_idx, out_idx, out, N);
        }
    }
}